// Round 2
// baseline (1040.342 us; speedup 1.0000x reference)
//
#include <hip/hip_runtime.h>
#include <hip/hip_bf16.h>
#include <cstdint>
#include <cstddef>

#define N_EXPERTS 8
#define HIDDEN    2048
#define EDIM      1408
#define UPCOLS    2816
#define NTOK      8192
#define CAP       8192
#define MAXMT     136   // max M-tiles: 16384/128 + 8

typedef __bf16 bf16x8 __attribute__((ext_vector_type(8)));
typedef __bf16 bf16x4 __attribute__((ext_vector_type(4)));
typedef float  f32x4  __attribute__((ext_vector_type(4)));

// ---- workspace layout (bytes) ----
#define TOK_OFF   4096
#define W_OFF     (TOK_OFF + (size_t)CAP * N_EXPERTS * 4)
#define XBF_OFF   (W_OFF + (size_t)CAP * N_EXPERTS * 4)
#define UPT_OFF   (XBF_OFF + (size_t)NTOK * HIDDEN * 2)
#define DNT_OFF   (UPT_OFF + (size_t)N_EXPERTS * UPCOLS * HIDDEN * 2)
#define HACT_OFF  (DNT_OFF + (size_t)N_EXPERTS * HIDDEN * EDIM * 2)
#define WS_NEEDED (HACT_OFF + (size_t)(MAXMT * 128) * EDIM * 2)
// total ~211.3 MiB

// meta (ints): [0..8) counts, [8] ntiles, [16..24) h-row offsets,
//              [32..168) tile->expert, [192..328) tile->local row0

__device__ __forceinline__ void gload16(const void* g, void* l) {
  __builtin_amdgcn_global_load_lds(
      (const __attribute__((address_space(1))) void*)g,
      (__attribute__((address_space(3))) void*)l, 16, 0, 0);
}

__global__ void build_entries(const int* __restrict__ idx,
                              const float* __restrict__ sc,
                              int* __restrict__ meta,
                              int* __restrict__ toks,
                              float* __restrict__ wts) {
  int t = blockIdx.x * blockDim.x + threadIdx.x;
  if (t >= NTOK) return;
  int e0 = idx[2 * t] & 7, e1 = idx[2 * t + 1] & 7;   // int32 per harness contract
  float s0 = sc[2 * t], s1 = sc[2 * t + 1];
  if (e0 == e1) {
    int p = atomicAdd(&meta[e0], 1);
    toks[e0 * CAP + p] = t; wts[e0 * CAP + p] = s0 + s1;
  } else {
    int p = atomicAdd(&meta[e0], 1);
    toks[e0 * CAP + p] = t; wts[e0 * CAP + p] = s0;
    p = atomicAdd(&meta[e1], 1);
    toks[e1 * CAP + p] = t; wts[e1 * CAP + p] = s1;
  }
}

__global__ void finalize_meta(int* __restrict__ meta,
                              int* __restrict__ toks,
                              float* __restrict__ wts) {
  __shared__ int c[8], pc[8];
  int tid = threadIdx.x;
  if (tid < 8) { c[tid] = meta[tid]; pc[tid] = ((c[tid] + 127) >> 7) << 7; }
  __syncthreads();
  if (tid == 0) {
    int off = 0, t = 0;
    for (int e = 0; e < 8; e++) {
      meta[16 + e] = off;
      int nt = pc[e] >> 7;
      for (int i = 0; i < nt; i++) { meta[32 + t] = e; meta[192 + t] = i * 128; t++; }
      off += pc[e];
    }
    meta[8] = t;
  }
  // pad entries to tile multiple with weight-0 token-0 rows
  for (int e = 0; e < 8; e++)
    for (int i = c[e] + tid; i < pc[e]; i += blockDim.x) {
      toks[e * CAP + i] = 0; wts[e * CAP + i] = 0.f;
    }
}

__global__ void cast_x(const float4* __restrict__ in, __bf16* __restrict__ o) {
  size_t i = (size_t)blockIdx.x * blockDim.x + threadIdx.x;
  float4 v = in[i];
  bf16x4 r = { (__bf16)v.x, (__bf16)v.y, (__bf16)v.z, (__bf16)v.w };
  ((bf16x4*)o)[i] = r;
}

// in: [E][K][N] fp32 -> out: [E][N][K] bf16  (N-major so GEMM B-frags are K-contiguous)
__global__ void transpose_cast(const float* __restrict__ in, __bf16* __restrict__ out,
                               int K, int N) {
  __shared__ float t[32][33];
  const size_t ebase = (size_t)blockIdx.z * K * N;
  const float* src = in + ebase;
  __bf16* dst = out + ebase;
  int x0 = blockIdx.x * 32, y0 = blockIdx.y * 32;
  int tx = threadIdx.x, ty = threadIdx.y;
#pragma unroll
  for (int i = 0; i < 4; i++)
    t[ty + 8 * i][tx] = src[(size_t)(y0 + ty + 8 * i) * N + x0 + tx];
  __syncthreads();
#pragma unroll
  for (int i = 0; i < 4; i++)
    dst[(size_t)(x0 + ty + 8 * i) * K + y0 + tx] = (__bf16)t[tx][ty + 8 * i];
}

// grouped GEMM: C[128 x (64 gate + 64 up)] per block, K=2048, fused SiLU*up -> hact bf16
__global__ __launch_bounds__(256, 2) void gemm_up(
    const __bf16* __restrict__ xb, const __bf16* __restrict__ upT,
    const int* __restrict__ meta, const int* __restrict__ toks,
    __bf16* __restrict__ hact) {
  const int mt = blockIdx.x;
  if (mt >= meta[8]) return;
  const int e = meta[32 + mt];
  const int row0 = meta[192 + mt];
  const int hbase = meta[16 + e];
  const int n0 = blockIdx.y * 64;

  __shared__ __bf16 lA[128 * 64];
  __shared__ __bf16 lBg[64 * 64];
  __shared__ __bf16 lBu[64 * 64];

  const int tid = threadIdx.x;
  const int lane = tid & 63, wave = tid >> 6;
  const int srow = tid >> 3;                 // staging row within 32-row round
  const int gch = (tid & 7) ^ (srow & 7);    // XOR-swizzled source chunk

  const __bf16* upE = upT + (size_t)e * UPCOLS * HIDDEN;

  size_t aoff[4];
#pragma unroll
  for (int r = 0; r < 4; r++) {
    int row = row0 + srow + 32 * r;
    int tok = toks[e * CAP + row];           // gathered token row
    aoff[r] = (size_t)tok * HIDDEN + gch * 8;
  }
  size_t bgoff[2], buoff[2];
#pragma unroll
  for (int r = 0; r < 2; r++) {
    int n = n0 + srow + 32 * r;
    bgoff[r] = (size_t)n * HIDDEN + gch * 8;
    buoff[r] = (size_t)(n + EDIM) * HIDDEN + gch * 8;
  }

  f32x4 accg[4][2] = {};
  f32x4 accu[4][2] = {};
  const int wrow = (wave >> 1) * 64;
  const int wcol = (wave & 1) * 32;
  const int l15 = lane & 15, quad = lane >> 4;

  for (int k0 = 0; k0 < HIDDEN; k0 += 64) {
    __syncthreads();
#pragma unroll
    for (int r = 0; r < 4; r++)
      gload16(xb + aoff[r] + k0, (char*)lA + r * 4096 + tid * 16);
#pragma unroll
    for (int r = 0; r < 2; r++) {
      gload16(upE + bgoff[r] + k0, (char*)lBg + r * 4096 + tid * 16);
      gload16(upE + buoff[r] + k0, (char*)lBu + r * 4096 + tid * 16);
    }
    __syncthreads();
#pragma unroll
    for (int kk = 0; kk < 2; kk++) {
      bf16x8 af[4], bg[2], bu[2];
#pragma unroll
      for (int mi = 0; mi < 4; mi++) {
        int row = wrow + mi * 16 + l15;
        int slot = (kk * 4 + quad) ^ (row & 7);
        af[mi] = *(const bf16x8*)((const char*)lA + row * 128 + slot * 16);
      }
#pragma unroll
      for (int ni = 0; ni < 2; ni++) {
        int row = wcol + ni * 16 + l15;
        int slot = (kk * 4 + quad) ^ (row & 7);
        bg[ni] = *(const bf16x8*)((const char*)lBg + row * 128 + slot * 16);
        bu[ni] = *(const bf16x8*)((const char*)lBu + row * 128 + slot * 16);
      }
#pragma unroll
      for (int mi = 0; mi < 4; mi++)
#pragma unroll
        for (int ni = 0; ni < 2; ni++) {
          accg[mi][ni] = __builtin_amdgcn_mfma_f32_16x16x32_bf16(af[mi], bg[ni], accg[mi][ni], 0, 0, 0);
          accu[mi][ni] = __builtin_amdgcn_mfma_f32_16x16x32_bf16(af[mi], bu[ni], accu[mi][ni], 0, 0, 0);
        }
    }
  }

#pragma unroll
  for (int mi = 0; mi < 4; mi++)
#pragma unroll
    for (int ni = 0; ni < 2; ni++)
#pragma unroll
      for (int v = 0; v < 4; v++) {
        int m = hbase + row0 + wrow + mi * 16 + quad * 4 + v;
        int n = n0 + wcol + ni * 16 + l15;
        float g = accg[mi][ni][v];
        float u = accu[mi][ni][v];
        float act = g / (1.f + __expf(-g)) * u;
        hact[(size_t)m * EDIM + n] = (__bf16)act;
      }
}

// grouped GEMM: y[128x128] = hact @ downT, scale by entry weight, atomicAdd into out
__global__ __launch_bounds__(256, 2) void gemm_down(
    const __bf16* __restrict__ hact, const __bf16* __restrict__ dnT,
    const int* __restrict__ meta, const int* __restrict__ toks,
    const float* __restrict__ wts, float* __restrict__ out) {
  const int mt = blockIdx.x;
  if (mt >= meta[8]) return;
  const int e = meta[32 + mt];
  const int row0 = meta[192 + mt];
  const int hbase = meta[16 + e];
  const int n0 = blockIdx.y * 128;

  __shared__ __bf16 lA[128 * 64];
  __shared__ __bf16 lB[128 * 64];

  const int tid = threadIdx.x;
  const int lane = tid & 63, wave = tid >> 6;
  const int srow = tid >> 3;
  const int gch = (tid & 7) ^ (srow & 7);

  const __bf16* dnE = dnT + (size_t)e * HIDDEN * EDIM;

  size_t aoff[4], boff[4];
#pragma unroll
  for (int r = 0; r < 4; r++) {
    int row = srow + 32 * r;
    aoff[r] = (size_t)(hbase + row0 + row) * EDIM + gch * 8;
    boff[r] = (size_t)(n0 + row) * EDIM + gch * 8;
  }

  f32x4 acc[4][4] = {};
  const int wrow = (wave >> 1) * 64;
  const int wcol = (wave & 1) * 64;
  const int l15 = lane & 15, quad = lane >> 4;

  for (int k0 = 0; k0 < EDIM; k0 += 64) {
    __syncthreads();
#pragma unroll
    for (int r = 0; r < 4; r++) {
      gload16(hact + aoff[r] + k0, (char*)lA + r * 4096 + tid * 16);
      gload16(dnE + boff[r] + k0, (char*)lB + r * 4096 + tid * 16);
    }
    __syncthreads();
#pragma unroll
    for (int kk = 0; kk < 2; kk++) {
      bf16x8 af[4], bfr[4];
#pragma unroll
      for (int mi = 0; mi < 4; mi++) {
        int row = wrow + mi * 16 + l15;
        int slot = (kk * 4 + quad) ^ (row & 7);
        af[mi] = *(const bf16x8*)((const char*)lA + row * 128 + slot * 16);
      }
#pragma unroll
      for (int ni = 0; ni < 4; ni++) {
        int row = wcol + ni * 16 + l15;
        int slot = (kk * 4 + quad) ^ (row & 7);
        bfr[ni] = *(const bf16x8*)((const char*)lB + row * 128 + slot * 16);
      }
#pragma unroll
      for (int mi = 0; mi < 4; mi++)
#pragma unroll
        for (int ni = 0; ni < 4; ni++)
          acc[mi][ni] = __builtin_amdgcn_mfma_f32_16x16x32_bf16(af[mi], bfr[ni], acc[mi][ni], 0, 0, 0);
    }
  }

#pragma unroll
  for (int mi = 0; mi < 4; mi++)
#pragma unroll
    for (int v = 0; v < 4; v++) {
      int rloc = row0 + wrow + mi * 16 + quad * 4 + v;
      int tok = toks[e * CAP + rloc];
      float w = wts[e * CAP + rloc];
#pragma unroll
      for (int ni = 0; ni < 4; ni++) {
        int n = n0 + wcol + ni * 16 + l15;
        atomicAdd(out + (size_t)tok * HIDDEN + n, acc[mi][ni][v] * w);
      }
    }
}

extern "C" void kernel_launch(void* const* d_in, const int* in_sizes, int n_in,
                              void* d_out, int out_size, void* d_ws, size_t ws_size,
                              hipStream_t stream) {
  const float* x = (const float*)d_in[0];
  const int* idx = (const int*)d_in[1];     // integer inputs arrive as int32
  const float* sc = (const float*)d_in[2];
  const float* up = (const float*)d_in[3];
  const float* dn = (const float*)d_in[4];
  float* out = (float*)d_out;
  char* ws = (char*)d_ws;

  // out must be zeroed every call (harness poisons it)
  hipMemsetAsync(out, 0, (size_t)out_size * sizeof(float), stream);
  if (ws_size < WS_NEEDED) return;  // diagnosable clean failure instead of a wild-write crash

  int* meta = (int*)ws;
  int* toks = (int*)(ws + TOK_OFF);
  float* wts = (float*)(ws + W_OFF);
  __bf16* xb = (__bf16*)(ws + XBF_OFF);
  __bf16* upT = (__bf16*)(ws + UPT_OFF);
  __bf16* dnT = (__bf16*)(ws + DNT_OFF);
  __bf16* hact = (__bf16*)(ws + HACT_OFF);

  hipMemsetAsync(meta, 0, 64, stream);

  build_entries<<<NTOK / 256, 256, 0, stream>>>(idx, sc, meta, toks, wts);
  finalize_meta<<<1, 256, 0, stream>>>(meta, toks, wts);
  cast_x<<<(NTOK * HIDDEN / 4) / 256, 256, 0, stream>>>((const float4*)x, xb);
  dim3 tb(32, 8);
  transpose_cast<<<dim3(UPCOLS / 32, HIDDEN / 32, N_EXPERTS), tb, 0, stream>>>(up, upT, HIDDEN, UPCOLS);
  transpose_cast<<<dim3(HIDDEN / 32, EDIM / 32, N_EXPERTS), tb, 0, stream>>>(dn, dnT, EDIM, HIDDEN);
  gemm_up<<<dim3(MAXMT, EDIM / 64), 256, 0, stream>>>(xb, upT, meta, toks, hact);
  gemm_down<<<dim3(MAXMT, HIDDEN / 128), 256, 0, stream>>>(hact, dnT, meta, toks, wts, out);
}

// Round 3
// 858.369 us; speedup vs baseline: 1.2120x; 1.2120x over previous
//
#include <hip/hip_runtime.h>
#include <hip/hip_bf16.h>
#include <cstdint>
#include <cstddef>

#define N_EXPERTS 8
#define HIDDEN    2048
#define EDIM      1408
#define UPCOLS    2816
#define NTOK      8192
#define CAP       8192
#define MAXMT     136   // max M-tiles: 16384/128 + 8

typedef __bf16 bf16x8 __attribute__((ext_vector_type(8)));
typedef __bf16 bf16x4 __attribute__((ext_vector_type(4)));
typedef float  f32x4  __attribute__((ext_vector_type(4)));

// ---- workspace layout (bytes) ----
#define EPOS_OFF  4096
#define TOK_OFF   (EPOS_OFF + (size_t)NTOK * 2 * 4)
#define W_OFF     (TOK_OFF + (size_t)CAP * N_EXPERTS * 4)
#define XBF_OFF   (W_OFF + (size_t)CAP * N_EXPERTS * 4)
#define UPT_OFF   (XBF_OFF + (size_t)NTOK * HIDDEN * 2)
#define DNT_OFF   (UPT_OFF + (size_t)N_EXPERTS * UPCOLS * HIDDEN * 2)
#define HACT_OFF  (DNT_OFF + (size_t)N_EXPERTS * HIDDEN * EDIM * 2)
#define WS_NEEDED (HACT_OFF + (size_t)(MAXMT * 128) * EDIM * 2)
// ybuf [MAXMT*128][HIDDEN] bf16 (71MB) aliases the upT region (92MB):
// upT is dead once gemm_up finishes; gemm_down writes ybuf, combine reads it.
#define YBUF_OFF  UPT_OFF

// meta (ints): [0..8) counts, [8] ntiles, [16..24) h-row offsets,
//              [32..168) tile->expert, [192..328) tile->local row0

__device__ __forceinline__ void gload16(const void* g, void* l) {
  __builtin_amdgcn_global_load_lds(
      (const __attribute__((address_space(1))) void*)g,
      (__attribute__((address_space(3))) void*)l, 16, 0, 0);
}

__global__ void build_entries(const int* __restrict__ idx,
                              const float* __restrict__ sc,
                              int* __restrict__ meta,
                              int* __restrict__ toks,
                              float* __restrict__ wts,
                              int* __restrict__ epos) {
  int t = blockIdx.x * blockDim.x + threadIdx.x;
  if (t >= NTOK) return;
  int e0 = idx[2 * t] & 7, e1 = idx[2 * t + 1] & 7;   // int32 per harness contract
  float s0 = sc[2 * t], s1 = sc[2 * t + 1];
  if (e0 == e1) {
    int p = atomicAdd(&meta[e0], 1);
    toks[e0 * CAP + p] = t; wts[e0 * CAP + p] = s0 + s1;
    epos[2 * t] = (e0 << 16) | p; epos[2 * t + 1] = -1;
  } else {
    int p0 = atomicAdd(&meta[e0], 1);
    toks[e0 * CAP + p0] = t; wts[e0 * CAP + p0] = s0;
    int p1 = atomicAdd(&meta[e1], 1);
    toks[e1 * CAP + p1] = t; wts[e1 * CAP + p1] = s1;
    epos[2 * t] = (e0 << 16) | p0; epos[2 * t + 1] = (e1 << 16) | p1;
  }
}

__global__ void finalize_meta(int* __restrict__ meta,
                              int* __restrict__ toks,
                              float* __restrict__ wts) {
  __shared__ int c[8], pc[8];
  int tid = threadIdx.x;
  if (tid < 8) { c[tid] = meta[tid]; pc[tid] = ((c[tid] + 127) >> 7) << 7; }
  __syncthreads();
  if (tid == 0) {
    int off = 0, t = 0;
    for (int e = 0; e < 8; e++) {
      meta[16 + e] = off;
      int nt = pc[e] >> 7;
      for (int i = 0; i < nt; i++) { meta[32 + t] = e; meta[192 + t] = i * 128; t++; }
      off += pc[e];
    }
    meta[8] = t;
  }
  // pad entries to tile multiple with weight-0 token-0 rows
  for (int e = 0; e < 8; e++)
    for (int i = c[e] + tid; i < pc[e]; i += blockDim.x) {
      toks[e * CAP + i] = 0; wts[e * CAP + i] = 0.f;
    }
}

__global__ void cast_x(const float4* __restrict__ in, __bf16* __restrict__ o) {
  size_t i = (size_t)blockIdx.x * blockDim.x + threadIdx.x;
  float4 v = in[i];
  bf16x4 r = { (__bf16)v.x, (__bf16)v.y, (__bf16)v.z, (__bf16)v.w };
  ((bf16x4*)o)[i] = r;
}

// in: [E][K][N] fp32 -> out: [E][N][K] bf16  (N-major so GEMM B-frags are K-contiguous)
__global__ void transpose_cast(const float* __restrict__ in, __bf16* __restrict__ out,
                               int K, int N) {
  __shared__ float t[32][33];
  const size_t ebase = (size_t)blockIdx.z * K * N;
  const float* src = in + ebase;
  __bf16* dst = out + ebase;
  int x0 = blockIdx.x * 32, y0 = blockIdx.y * 32;
  int tx = threadIdx.x, ty = threadIdx.y;
#pragma unroll
  for (int i = 0; i < 4; i++)
    t[ty + 8 * i][tx] = src[(size_t)(y0 + ty + 8 * i) * N + x0 + tx];
  __syncthreads();
#pragma unroll
  for (int i = 0; i < 4; i++)
    dst[(size_t)(x0 + ty + 8 * i) * K + y0 + tx] = (__bf16)t[tx][ty + 8 * i];
}

// grouped GEMM: C[128 x (64 gate + 64 up)] per block, K=2048, fused SiLU*up -> hact bf16
__global__ __launch_bounds__(256, 4) void gemm_up(
    const __bf16* __restrict__ xb, const __bf16* __restrict__ upT,
    const int* __restrict__ meta, const int* __restrict__ toks,
    __bf16* __restrict__ hact) {
  const int mt = blockIdx.x;
  if (mt >= meta[8]) return;
  const int e = meta[32 + mt];
  const int row0 = meta[192 + mt];
  const int hbase = meta[16 + e];
  const int n0 = blockIdx.y * 64;

  __shared__ __bf16 lA[128 * 64];
  __shared__ __bf16 lBg[64 * 64];
  __shared__ __bf16 lBu[64 * 64];

  const int tid = threadIdx.x;
  const int lane = tid & 63, wave = tid >> 6;
  const int srow = tid >> 3;                 // staging row within 32-row round
  const int gch = (tid & 7) ^ (srow & 7);    // XOR-swizzled source chunk

  const __bf16* upE = upT + (size_t)e * UPCOLS * HIDDEN;

  size_t aoff[4];
#pragma unroll
  for (int r = 0; r < 4; r++) {
    int row = row0 + srow + 32 * r;
    int tok = toks[e * CAP + row];           // gathered token row
    aoff[r] = (size_t)tok * HIDDEN + gch * 8;
  }
  size_t bgoff[2], buoff[2];
#pragma unroll
  for (int r = 0; r < 2; r++) {
    int n = n0 + srow + 32 * r;
    bgoff[r] = (size_t)n * HIDDEN + gch * 8;
    buoff[r] = (size_t)(n + EDIM) * HIDDEN + gch * 8;
  }

  f32x4 accg[4][2] = {};
  f32x4 accu[4][2] = {};
  const int wrow = (wave >> 1) * 64;
  const int wcol = (wave & 1) * 32;
  const int l15 = lane & 15, quad = lane >> 4;

  for (int k0 = 0; k0 < HIDDEN; k0 += 64) {
    __syncthreads();
#pragma unroll
    for (int r = 0; r < 4; r++)
      gload16(xb + aoff[r] + k0, (char*)lA + r * 4096 + tid * 16);
#pragma unroll
    for (int r = 0; r < 2; r++) {
      gload16(upE + bgoff[r] + k0, (char*)lBg + r * 4096 + tid * 16);
      gload16(upE + buoff[r] + k0, (char*)lBu + r * 4096 + tid * 16);
    }
    __syncthreads();
#pragma unroll
    for (int kk = 0; kk < 2; kk++) {
      bf16x8 af[4], bg[2], bu[2];
#pragma unroll
      for (int mi = 0; mi < 4; mi++) {
        int row = wrow + mi * 16 + l15;
        int slot = (kk * 4 + quad) ^ (row & 7);
        af[mi] = *(const bf16x8*)((const char*)lA + row * 128 + slot * 16);
      }
#pragma unroll
      for (int ni = 0; ni < 2; ni++) {
        int row = wcol + ni * 16 + l15;
        int slot = (kk * 4 + quad) ^ (row & 7);
        bg[ni] = *(const bf16x8*)((const char*)lBg + row * 128 + slot * 16);
        bu[ni] = *(const bf16x8*)((const char*)lBu + row * 128 + slot * 16);
      }
#pragma unroll
      for (int mi = 0; mi < 4; mi++)
#pragma unroll
        for (int ni = 0; ni < 2; ni++) {
          accg[mi][ni] = __builtin_amdgcn_mfma_f32_16x16x32_bf16(af[mi], bg[ni], accg[mi][ni], 0, 0, 0);
          accu[mi][ni] = __builtin_amdgcn_mfma_f32_16x16x32_bf16(af[mi], bu[ni], accu[mi][ni], 0, 0, 0);
        }
    }
  }

#pragma unroll
  for (int mi = 0; mi < 4; mi++)
#pragma unroll
    for (int ni = 0; ni < 2; ni++)
#pragma unroll
      for (int v = 0; v < 4; v++) {
        int m = hbase + row0 + wrow + mi * 16 + quad * 4 + v;
        int n = n0 + wcol + ni * 16 + l15;
        float g = accg[mi][ni][v];
        float u = accu[mi][ni][v];
        float act = g / (1.f + __expf(-g)) * u;
        hact[(size_t)m * EDIM + n] = (__bf16)act;
      }
}

// grouped GEMM: y[128x128] = hact @ downT, scale rows by entry weight,
// plain bf16 stores into ybuf (no atomics) — combine() gathers per token.
__global__ __launch_bounds__(256, 4) void gemm_down(
    const __bf16* __restrict__ hact, const __bf16* __restrict__ dnT,
    const int* __restrict__ meta, const float* __restrict__ wts,
    __bf16* __restrict__ ybuf) {
  const int mt = blockIdx.x;
  if (mt >= meta[8]) return;
  const int e = meta[32 + mt];
  const int row0 = meta[192 + mt];
  const int hbase = meta[16 + e];
  const int n0 = blockIdx.y * 128;

  __shared__ __bf16 lA[128 * 64];
  __shared__ __bf16 lB[128 * 64];

  const int tid = threadIdx.x;
  const int lane = tid & 63, wave = tid >> 6;
  const int srow = tid >> 3;
  const int gch = (tid & 7) ^ (srow & 7);

  const __bf16* dnE = dnT + (size_t)e * HIDDEN * EDIM;

  size_t aoff[4], boff[4];
#pragma unroll
  for (int r = 0; r < 4; r++) {
    int row = srow + 32 * r;
    aoff[r] = (size_t)(hbase + row0 + row) * EDIM + gch * 8;
    boff[r] = (size_t)(n0 + row) * EDIM + gch * 8;
  }

  f32x4 acc[4][4] = {};
  const int wrow = (wave >> 1) * 64;
  const int wcol = (wave & 1) * 64;
  const int l15 = lane & 15, quad = lane >> 4;

  for (int k0 = 0; k0 < EDIM; k0 += 64) {
    __syncthreads();
#pragma unroll
    for (int r = 0; r < 4; r++) {
      gload16(hact + aoff[r] + k0, (char*)lA + r * 4096 + tid * 16);
      gload16(dnE + boff[r] + k0, (char*)lB + r * 4096 + tid * 16);
    }
    __syncthreads();
#pragma unroll
    for (int kk = 0; kk < 2; kk++) {
      bf16x8 af[4], bfr[4];
#pragma unroll
      for (int mi = 0; mi < 4; mi++) {
        int row = wrow + mi * 16 + l15;
        int slot = (kk * 4 + quad) ^ (row & 7);
        af[mi] = *(const bf16x8*)((const char*)lA + row * 128 + slot * 16);
      }
#pragma unroll
      for (int ni = 0; ni < 4; ni++) {
        int row = wcol + ni * 16 + l15;
        int slot = (kk * 4 + quad) ^ (row & 7);
        bfr[ni] = *(const bf16x8*)((const char*)lB + row * 128 + slot * 16);
      }
#pragma unroll
      for (int mi = 0; mi < 4; mi++)
#pragma unroll
        for (int ni = 0; ni < 4; ni++)
          acc[mi][ni] = __builtin_amdgcn_mfma_f32_16x16x32_bf16(af[mi], bfr[ni], acc[mi][ni], 0, 0, 0);
    }
  }

#pragma unroll
  for (int mi = 0; mi < 4; mi++)
#pragma unroll
    for (int v = 0; v < 4; v++) {
      int rloc = row0 + wrow + mi * 16 + quad * 4 + v;
      float w = wts[e * CAP + rloc];
      size_t g = (size_t)(hbase + rloc) * HIDDEN;
#pragma unroll
      for (int ni = 0; ni < 4; ni++) {
        int n = n0 + wcol + ni * 16 + l15;
        ybuf[g + n] = (__bf16)(acc[mi][ni][v] * w);
      }
    }
}

// per token: out[t] = ybuf[row(entry0)] + ybuf[row(entry1)]  (fp32 out)
__global__ __launch_bounds__(256) void combine(
    const __bf16* __restrict__ ybuf, const int* __restrict__ epos,
    const int* __restrict__ meta, float* __restrict__ out) {
  const int t = blockIdx.x;
  const int c = threadIdx.x * 8;  // 256 threads x 8 elems = 2048 cols
  const int p0 = epos[2 * t], p1 = epos[2 * t + 1];
  const int e0 = p0 >> 16;
  const size_t g0 = (size_t)(meta[16 + e0] + (p0 & 0xffff)) * HIDDEN;
  bf16x8 y0 = *(const bf16x8*)(ybuf + g0 + c);
  float acc[8];
#pragma unroll
  for (int j = 0; j < 8; j++) acc[j] = (float)y0[j];
  if (p1 >= 0) {
    const int e1 = p1 >> 16;
    const size_t g1 = (size_t)(meta[16 + e1] + (p1 & 0xffff)) * HIDDEN;
    bf16x8 y1 = *(const bf16x8*)(ybuf + g1 + c);
#pragma unroll
    for (int j = 0; j < 8; j++) acc[j] += (float)y1[j];
  }
  float4* o = (float4*)(out + (size_t)t * HIDDEN + c);
  o[0] = make_float4(acc[0], acc[1], acc[2], acc[3]);
  o[1] = make_float4(acc[4], acc[5], acc[6], acc[7]);
}

extern "C" void kernel_launch(void* const* d_in, const int* in_sizes, int n_in,
                              void* d_out, int out_size, void* d_ws, size_t ws_size,
                              hipStream_t stream) {
  const float* x = (const float*)d_in[0];
  const int* idx = (const int*)d_in[1];     // integer inputs arrive as int32
  const float* sc = (const float*)d_in[2];
  const float* up = (const float*)d_in[3];
  const float* dn = (const float*)d_in[4];
  float* out = (float*)d_out;
  char* ws = (char*)d_ws;

  if (ws_size < WS_NEEDED) return;  // diagnosable clean failure

  int* meta = (int*)ws;
  int* epos = (int*)(ws + EPOS_OFF);
  int* toks = (int*)(ws + TOK_OFF);
  float* wts = (float*)(ws + W_OFF);
  __bf16* xb = (__bf16*)(ws + XBF_OFF);
  __bf16* upT = (__bf16*)(ws + UPT_OFF);
  __bf16* dnT = (__bf16*)(ws + DNT_OFF);
  __bf16* hact = (__bf16*)(ws + HACT_OFF);
  __bf16* ybuf = (__bf16*)(ws + YBUF_OFF);   // aliases upT (dead after gemm_up)

  hipMemsetAsync(meta, 0, 64, stream);

  build_entries<<<NTOK / 256, 256, 0, stream>>>(idx, sc, meta, toks, wts, epos);
  finalize_meta<<<1, 256, 0, stream>>>(meta, toks, wts);
  cast_x<<<(NTOK * HIDDEN / 4) / 256, 256, 0, stream>>>((const float4*)x, xb);
  dim3 tb(32, 8);
  transpose_cast<<<dim3(UPCOLS / 32, HIDDEN / 32, N_EXPERTS), tb, 0, stream>>>(up, upT, HIDDEN, UPCOLS);
  transpose_cast<<<dim3(HIDDEN / 32, EDIM / 32, N_EXPERTS), tb, 0, stream>>>(dn, dnT, EDIM, HIDDEN);
  gemm_up<<<dim3(MAXMT, EDIM / 64), 256, 0, stream>>>(xb, upT, meta, toks, hact);
  gemm_down<<<dim3(MAXMT, HIDDEN / 128), 256, 0, stream>>>(hact, dnT, meta, wts, ybuf);
  combine<<<NTOK, 256, 0, stream>>>(ybuf, epos, meta, out);
}